// Round 10
// baseline (137.361 us; speedup 1.0000x reference)
//
#include <hip/hip_runtime.h>
#include <hip/hip_bf16.h>
#include <stdint.h>

#define BATCH  32
#define CDIM   384
#define NTOK   1024
#define NHEADS 8
#define DH     48

using f32x4  = __attribute__((ext_vector_type(4))) float;
using bf16x8 = __attribute__((ext_vector_type(8))) short;
using u16x4  = __attribute__((ext_vector_type(4))) uint16_t;
using u16x8  = __attribute__((ext_vector_type(8))) uint16_t;

__device__ __forceinline__ uint16_t f2bf(float f) {
  __hip_bfloat16 h = __float2bfloat16(f);
  return *reinterpret_cast<uint16_t*>(&h);
}
__device__ __forceinline__ float bf2f(uint16_t u) {
  return __uint_as_float(((uint32_t)u) << 16);
}

#define GLL16(gsrc, ldst)                                                    \
  __builtin_amdgcn_global_load_lds(                                          \
      (const __attribute__((address_space(1))) void*)(gsrc),                 \
      (__attribute__((address_space(3))) void*)(ldst), 16, 0, 0)

// ---------------- kernel 0: weights f32 -> bf16 ----------------
__global__ __launch_bounds__(256) void k_convert_w(const float* __restrict__ wqkv,
                                                   const float* __restrict__ wproj,
                                                   uint16_t* __restrict__ wq,
                                                   uint16_t* __restrict__ wp) {
  int n1 = 3 * CDIM * CDIM;
  int n2 = CDIM * CDIM;
  int stride = gridDim.x * 256;
  for (int i = blockIdx.x * 256 + threadIdx.x; i < n1 + n2; i += stride) {
    if (i < n1) wq[i] = f2bf(wqkv[i]);
    else        wp[i - n1] = f2bf(wproj[i - n1]);
  }
}

// ------------- kernel 1: FUSED transpose + QKV GEMM -------------------------
// One block per 128-token panel (grid 256, 512 thr, 130KB LDS -> 1 block/CU).
// Phase 1: GLL16-stage x (f32, token-contiguous) in 6 chunks of 64 channels;
//   LDS-transpose -> bf16 into RESIDENT B-panel lB[128 tok][392] (384 data,
//   row pad 8 elems -> bank spread 17*row mod 32; 8-elem slots XOR-swizzled
//   s^(tok&7), same involution on phase-2 reads). Also writes xbf (B,C,N).
// Phase 2: for bm in 0..9: dbuf-stage A-tile chunks (16KB, L2-hot W) with
//   issue-early + single vmcnt(0)+barrier per K-step; MFMA vs resident lB.
// Eliminates xT entirely (24MB write + ~42MB HBM refetch + 50MB x re-read).
__global__ __launch_bounds__(512) void k_qkv_fused(const float* __restrict__ x,
                                                   const uint16_t* __restrict__ Wq,
                                                   const float* __restrict__ bqkv,
                                                   uint16_t* __restrict__ qk,
                                                   uint16_t* __restrict__ vT,
                                                   uint16_t* __restrict__ xbf,
                                                   int use_xbf) {
  __shared__ uint8_t smem[133120];
  uint16_t* lB  = (uint16_t*)smem;                        // 128 x 392 elems = 100352 B
  float*    xf  = (float*)(smem + 100352);                // phase 1: 64x128 f32 = 32 KB
  uint16_t* lA0 = (uint16_t*)(smem + 100352);             // phase 2: A dbuf (reuses xf)
  uint16_t* lA1 = (uint16_t*)(smem + 100352 + 16384);

  int tid = threadIdx.x;
  int jt  = blockIdx.x;                 // [0,256) token panels; no sharing -> no swizzle
  int b = jt >> 3, n0 = (jt & 7) * 128;
  const float* xsrc = x + (size_t)b * CDIM * NTOK + n0;   // + c*1024 + n

  // ---------------- phase 1: build resident B panel ----------------
  for (int ck = 0; ck < 6; ++ck) {
    int c0 = ck * 64;
#pragma unroll
    for (int i = 0; i < 4; ++i) {
      int ch = tid + 512 * i;            // [0,2048) 16B chunks, LDS dest linear
      int r  = ch >> 5;                  // channel row 0..63
      int cc = (ch & 31) * 4;            // f32 token col
      GLL16(xsrc + (size_t)(c0 + r) * NTOK + cc, (uint16_t*)xf + (size_t)ch * 8);
    }
    asm volatile("s_waitcnt vmcnt(0)" ::: "memory");
    __syncthreads();
    {
      int n = tid & 127, coct = tid >> 7;    // token, 16-channel group
      float v[16];
#pragma unroll
      for (int j = 0; j < 16; ++j) v[j] = xf[(size_t)(coct * 16 + j) * 128 + n];
#pragma unroll
      for (int g2 = 0; g2 < 2; ++g2) {
        u16x8 pk;
#pragma unroll
        for (int j = 0; j < 8; ++j) pk[j] = f2bf(v[g2 * 8 + j]);
        int s   = coct * 2 + g2;                       // slot in this 64-K block
        int off = c0 + ((s ^ (n & 7)) << 3);           // XOR swizzle (write side)
        *(u16x8*)(lB + (size_t)n * 392 + off) = pk;
      }
    }
    if (use_xbf) {
      int cr = tid >> 3;                 // 0..63
      int nc = (tid & 7) * 16;           // 0..112
      uint16_t* dst = xbf + (size_t)b * CDIM * NTOK + (size_t)(c0 + cr) * NTOK + n0 + nc;
#pragma unroll
      for (int q = 0; q < 2; ++q) {
        u16x8 pk;
#pragma unroll
        for (int j = 0; j < 8; ++j) pk[j] = f2bf(xf[(size_t)cr * 128 + nc + q * 8 + j]);
        *(u16x8*)(dst + q * 8) = pk;
      }
    }
    __syncthreads();                     // xf free for next chunk; lB writes visible
  }

  // ---------------- phase 2: GEMM over full M ----------------
  int w = tid >> 6, lane = tid & 63;
  int wr = w >> 1, wc = w & 1;           // 4M x 2N wave grid; wave-tile 32 x 64
  int lr = lane & 15, g = lane >> 4;

  for (int bm = 0; bm < 9; ++bm) {
    const uint16_t* A = Wq + (size_t)bm * 128 * 384;
    f32x4 acc[2][4];
#pragma unroll
    for (int i = 0; i < 2; ++i)
#pragma unroll
      for (int j = 0; j < 4; ++j) acc[i][j] = (f32x4){0.f, 0.f, 0.f, 0.f};

#pragma unroll
    for (int i = 0; i < 2; ++i) {        // stage kt=0 into lA0
      int ch = tid + 512 * i;            // [0,1024)
      int r  = ch >> 3;
      int cs = (((ch & 7) ^ (r & 7)) << 3);
      GLL16(A + (size_t)r * 384 + cs, lA0 + (size_t)ch * 8);
    }
    asm volatile("s_waitcnt vmcnt(0)" ::: "memory");
    __builtin_amdgcn_s_barrier();
#pragma unroll
    for (int t = 0; t < 6; ++t) {
      uint16_t* cur = (t & 1) ? lA1 : lA0;
      uint16_t* nxt = (t & 1) ? lA0 : lA1;
      if (t < 5) {
#pragma unroll
        for (int i = 0; i < 2; ++i) {    // issue next A chunk early
          int ch = tid + 512 * i;
          int r  = ch >> 3;
          int cs = (((ch & 7) ^ (r & 7)) << 3);
          GLL16(A + (size_t)r * 384 + (t + 1) * 64 + cs, nxt + (size_t)ch * 8);
        }
      }
      int kt = t * 64;
#pragma unroll
      for (int ks = 0; ks < 2; ++ks) {
        bf16x8 af[2], bfr[4];
#pragma unroll
        for (int mt = 0; mt < 2; ++mt) {
          int row = wr * 32 + mt * 16 + lr;
          int sl  = (((ks * 4 + g) ^ (row & 7)) << 3);
          af[mt] = *(const bf16x8*)(cur + (size_t)row * 64 + sl);
        }
#pragma unroll
        for (int nt = 0; nt < 4; ++nt) {
          int row = wc * 64 + nt * 16 + lr;            // token row
          int off = kt + (((ks * 4 + g) ^ (row & 7)) << 3);  // XOR (read side)
          bfr[nt] = *(const bf16x8*)(lB + (size_t)row * 392 + off);
        }
#pragma unroll
        for (int mt = 0; mt < 2; ++mt)
#pragma unroll
          for (int nt = 0; nt < 4; ++nt)
            acc[mt][nt] = __builtin_amdgcn_mfma_f32_16x16x32_bf16(af[mt], bfr[nt], acc[mt][nt], 0, 0, 0);
      }
      asm volatile("s_waitcnt vmcnt(0)" ::: "memory");
      __builtin_amdgcn_s_barrier();
    }

    // epilogue for this bm
    int o0 = bm * 128;
#pragma unroll
    for (int mt = 0; mt < 2; ++mt) {
      int ob = o0 + wr * 32 + mt * 16 + g * 4;   // 4 consecutive output rows
      float b0 = bqkv[ob + 0], b1 = bqkv[ob + 1], b2 = bqkv[ob + 2], b3 = bqkv[ob + 3];
#pragma unroll
      for (int nt = 0; nt < 4; ++nt) {
        int n = n0 + wc * 64 + nt * 16 + lr;     // token within batch b
        f32x4 v = acc[mt][nt];
        float v0 = v[0] + b0, v1 = v[1] + b1, v2 = v[2] + b2, v3 = v[3] + b3;
        if (ob < 768) {
          uint16_t* dst = qk + ((size_t)(b * 768 + ob) * 1024 + n);
          dst[0] = f2bf(v0); dst[1024] = f2bf(v1); dst[2048] = f2bf(v2); dst[3072] = f2bf(v3);
        } else {
          int oc = ob - 768;
          int h = oc / 48, d = oc % 48;          // 4-pack never crosses a head
          u16x4 p;
          p[0] = f2bf(v0); p[1] = f2bf(v1); p[2] = f2bf(v2); p[3] = f2bf(v3);
          *(u16x4*)(vT + ((size_t)((b * 8 + h) * 1024 + n) * 48 + d)) = p;
        }
      }
    }
  }
}

// ---------------- shared 128x128 GEMM mainloop for k_proj (K=384, BK=64) -----
__device__ __forceinline__ void gemm_tile_128(const uint16_t* __restrict__ A,
                                              const uint16_t* __restrict__ B,
                                              uint16_t* ldsA, uint16_t* ldsB,
                                              f32x4 acc[4][4], int tid) {
  const int K = 384;
  int w = tid >> 6, lane = tid & 63;
  int wr = w >> 1, wc = w & 1;
  int lr = lane & 15, g = lane >> 4;
  for (int kt = 0; kt < K; kt += 64) {
    __syncthreads();
#pragma unroll
    for (int iss = 0; iss < 4; ++iss) {
      int ch = tid + 256 * iss;
      int r  = ch >> 3;
      int cs = (((ch & 7) ^ (r & 7)) << 3);
      GLL16(A + (size_t)r * K + kt + cs, ldsA + (size_t)ch * 8);
      GLL16(B + (size_t)r * K + kt + cs, ldsB + (size_t)ch * 8);
    }
    __syncthreads();
#pragma unroll
    for (int ks = 0; ks < 2; ++ks) {
      bf16x8 af[4], bfr[4];
#pragma unroll
      for (int mt = 0; mt < 4; ++mt) {
        int row = wr * 64 + mt * 16 + lr;
        int sl  = (((ks * 4 + g) ^ (row & 7)) << 3);
        af[mt] = *(const bf16x8*)(ldsA + (size_t)row * 64 + sl);
      }
#pragma unroll
      for (int nt = 0; nt < 4; ++nt) {
        int row = wc * 64 + nt * 16 + lr;
        int sl  = (((ks * 4 + g) ^ (row & 7)) << 3);
        bfr[nt] = *(const bf16x8*)(ldsB + (size_t)row * 64 + sl);
      }
#pragma unroll
      for (int mt = 0; mt < 4; ++mt)
#pragma unroll
        for (int nt = 0; nt < 4; ++nt)
          acc[mt][nt] = __builtin_amdgcn_mfma_f32_16x16x32_bf16(af[mt], bfr[nt], acc[mt][nt], 0, 0, 0);
    }
  }
}

// ---------------- kernel 2: per-(b,h) channel attention (8 waves) ------------
__global__ __launch_bounds__(512) void k_attn(const uint16_t* __restrict__ qk,
                                              const uint16_t* __restrict__ vT,
                                              const float* __restrict__ temperature,
                                              uint16_t* __restrict__ aT) {
  __shared__ float Sp[8][48][49];
  __shared__ float Sf[48][49];
  __shared__ uint16_t P[48][72];
  __shared__ float nrm[96];
  int tid = threadIdx.x, w = tid >> 6, lane = tid & 63;
  int bh = blockIdx.x, b = bh >> 3, h = bh & 7;
  const uint16_t* qbase = qk + (size_t)(b * 768 + h * 48) * 1024;
  const uint16_t* kbase = qbase + (size_t)384 * 1024;

  for (int r = w; r < 96; r += 8) {
    const uint16_t* row = (r < 48) ? (qbase + (size_t)r * 1024)
                                   : (kbase + (size_t)(r - 48) * 1024);
    float s = 0.f;
#pragma unroll
    for (int jj = 0; jj < 4; ++jj) {
      u16x4 u = *(const u16x4*)(row + (size_t)(jj * 64 + lane) * 4);
#pragma unroll
      for (int e = 0; e < 4; ++e) { float f = bf2f(u[e]); s += f * f; }
    }
#pragma unroll
    for (int off = 32; off > 0; off >>= 1) s += __shfl_down(s, off);
    if (lane == 0) nrm[r] = fmaxf(sqrtf(s), 1e-12f);
  }

  int lr = lane & 15, g = lane >> 4;
  int nbase = w * 128;
  f32x4 sacc[3][3];
#pragma unroll
  for (int i = 0; i < 3; ++i)
#pragma unroll
    for (int j = 0; j < 3; ++j) sacc[i][j] = (f32x4){0.f, 0.f, 0.f, 0.f};
#pragma unroll
  for (int ks = 0; ks < 4; ++ks) {
    bf16x8 aq[3], bk[3];
#pragma unroll
    for (int mt = 0; mt < 3; ++mt)
      aq[mt] = *(const bf16x8*)(qbase + (size_t)(mt * 16 + lr) * 1024 + nbase + ks * 32 + g * 8);
#pragma unroll
    for (int et = 0; et < 3; ++et)
      bk[et] = *(const bf16x8*)(kbase + (size_t)(et * 16 + lr) * 1024 + nbase + ks * 32 + g * 8);
#pragma unroll
    for (int mt = 0; mt < 3; ++mt)
#pragma unroll
      for (int et = 0; et < 3; ++et)
        sacc[mt][et] = __builtin_amdgcn_mfma_f32_16x16x32_bf16(aq[mt], bk[et], sacc[mt][et], 0, 0, 0);
  }
#pragma unroll
  for (int mt = 0; mt < 3; ++mt)
#pragma unroll
    for (int et = 0; et < 3; ++et)
#pragma unroll
      for (int r = 0; r < 4; ++r)
        Sp[w][mt * 16 + g * 4 + r][et * 16 + lr] = sacc[mt][et][r];
  __syncthreads();

  float temp = temperature[h];
  for (int idx = tid; idx < 48 * 48; idx += 512) {
    int d = idx / 48, e = idx - d * 48;
    float s = 0.f;
#pragma unroll
    for (int ww = 0; ww < 8; ++ww) s += Sp[ww][d][e];
    Sf[d][e] = s * temp / (nrm[d] * nrm[48 + e]);
  }
  __syncthreads();

  if (tid < 48) {
    int d = tid;
    float m = -1e30f;
    for (int e = 0; e < 48; ++e) m = fmaxf(m, Sf[d][e]);
    float sum = 0.f;
    for (int e = 0; e < 48; ++e) { float v = __expf(Sf[d][e] - m); sum += v; Sf[d][e] = v; }
    float inv = 1.f / sum;
    for (int e = 0; e < 48; ++e) P[d][e] = f2bf(Sf[d][e] * inv);
    for (int e = 48; e < 64; ++e) P[d][e] = 0;
  }
  __syncthreads();

  bf16x8 af[3][2];
#pragma unroll
  for (int mt = 0; mt < 3; ++mt)
#pragma unroll
    for (int ks = 0; ks < 2; ++ks)
      af[mt][ks] = *(const bf16x8*)(&P[mt * 16 + lr][ks * 32 + g * 8]);
  const uint16_t* vb = vT + (size_t)(b * 8 + h) * 1024 * 48;
  bf16x8 zf;
#pragma unroll
  for (int i = 0; i < 8; ++i) zf[i] = 0;
#pragma unroll
  for (int nt = 0; nt < 8; ++nt) {
    int n = w * 128 + nt * 16 + lr;
    bf16x8 bv[2];
    bv[0] = *(const bf16x8*)(vb + (size_t)n * 48 + g * 8);
    int eb1 = 32 + g * 8;
    bv[1] = (eb1 < 48) ? *(const bf16x8*)(vb + (size_t)n * 48 + eb1) : zf;
    f32x4 o[3];
#pragma unroll
    for (int mt = 0; mt < 3; ++mt) o[mt] = (f32x4){0.f, 0.f, 0.f, 0.f};
#pragma unroll
    for (int ks = 0; ks < 2; ++ks)
#pragma unroll
      for (int mt = 0; mt < 3; ++mt)
        o[mt] = __builtin_amdgcn_mfma_f32_16x16x32_bf16(af[mt][ks], bv[ks], o[mt], 0, 0, 0);
#pragma unroll
    for (int mt = 0; mt < 3; ++mt) {
      int c = h * 48 + mt * 16 + g * 4;
      u16x4 p;
#pragma unroll
      for (int r = 0; r < 4; ++r) p[r] = f2bf(o[mt][r]);
      *(u16x4*)(aT + ((size_t)(b * 1024 + n) * 384 + c)) = p;
    }
  }
}

// ---------------- kernel 3: proj GEMM + bias + residual ----------------
__global__ __launch_bounds__(256) void k_proj(const uint16_t* __restrict__ Wp,
                                              const uint16_t* __restrict__ aT,
                                              const float* __restrict__ bproj,
                                              const uint16_t* __restrict__ xbf,
                                              const float* __restrict__ x,
                                              float* __restrict__ out,
                                              int use_xbf) {
  __shared__ uint16_t ldsA[128 * 64];
  __shared__ uint16_t ldsB[128 * 64];
  int tid = threadIdx.x;
  int id  = blockIdx.x;
  int xcd = id & 7, idx = id >> 3;
  int jt  = xcd * 32 + (idx & 31);
  int bm  = idx >> 5;
  int o0 = bm * 128, j0 = jt * 128;
  f32x4 acc[4][4];
#pragma unroll
  for (int i = 0; i < 4; ++i)
#pragma unroll
    for (int j = 0; j < 4; ++j) acc[i][j] = (f32x4){0.f, 0.f, 0.f, 0.f};

  gemm_tile_128(Wp + (size_t)o0 * 384, aT + (size_t)j0 * 384, ldsA, ldsB, acc, tid);

  int w = tid >> 6, lane = tid & 63;
  int wr = w >> 1, wc = w & 1, lr = lane & 15, g = lane >> 4;
#pragma unroll
  for (int mt = 0; mt < 4; ++mt) {
    int ob = o0 + wr * 64 + mt * 16 + g * 4;
    float b0 = bproj[ob + 0], b1 = bproj[ob + 1], b2 = bproj[ob + 2], b3 = bproj[ob + 3];
#pragma unroll
    for (int nt = 0; nt < 4; ++nt) {
      int j = j0 + wc * 64 + nt * 16 + lr;
      int b = j >> 10, n = j & 1023;
      f32x4 v = acc[mt][nt];
      size_t i0 = (size_t)(b * 384 + ob) * 1024 + n;
      float r0, r1, r2, r3;
      if (use_xbf) {
        r0 = bf2f(xbf[i0]); r1 = bf2f(xbf[i0 + 1024]);
        r2 = bf2f(xbf[i0 + 2048]); r3 = bf2f(xbf[i0 + 3072]);
      } else {
        r0 = x[i0]; r1 = x[i0 + 1024]; r2 = x[i0 + 2048]; r3 = x[i0 + 3072];
      }
      __builtin_nontemporal_store(v[0] + b0 + r0, &out[i0]);
      __builtin_nontemporal_store(v[1] + b1 + r1, &out[i0 + 1024]);
      __builtin_nontemporal_store(v[2] + b2 + r2, &out[i0 + 2048]);
      __builtin_nontemporal_store(v[3] + b3 + r3, &out[i0 + 3072]);
    }
  }
}

extern "C" void kernel_launch(void* const* d_in, const int* in_sizes, int n_in,
                              void* d_out, int out_size, void* d_ws, size_t ws_size,
                              hipStream_t stream) {
  const float* x     = (const float*)d_in[0];
  const float* wqkv  = (const float*)d_in[1];
  const float* bqkv  = (const float*)d_in[2];
  const float* temp  = (const float*)d_in[3];
  const float* wproj = (const float*)d_in[4];
  const float* bproj = (const float*)d_in[5];
  float* out = (float*)d_out;

  char* ws = (char*)d_ws;
  size_t off = 0;
  auto alloc = [&](size_t bytes) -> char* {
    char* p = ws + off;
    off += (bytes + 255) & ~(size_t)255;
    return p;
  };
  uint16_t* wq_bf = (uint16_t*)alloc((size_t)3 * CDIM * CDIM * 2);
  uint16_t* wp_bf = (uint16_t*)alloc((size_t)CDIM * CDIM * 2);
  uint16_t* qkbuf = (uint16_t*)alloc((size_t)BATCH * 768 * NTOK * 2);         // 48 MB
  uint16_t* vTbuf = (uint16_t*)alloc((size_t)BATCH * NHEADS * NTOK * DH * 2); // 24 MB
  uint16_t* aT    = (uint16_t*)alloc((size_t)BATCH * NTOK * CDIM * 2);        // 24 MB
  size_t xbf_bytes = (size_t)BATCH * CDIM * NTOK * 2;                         // 24 MB
  int use_xbf = (off + xbf_bytes <= ws_size) ? 1 : 0;
  uint16_t* xbf = use_xbf ? (uint16_t*)alloc(xbf_bytes) : (uint16_t*)aT; // dummy if unused

  k_convert_w<<<dim3(576), dim3(256), 0, stream>>>(wqkv, wproj, wq_bf, wp_bf);
  k_qkv_fused<<<dim3(256), dim3(512), 0, stream>>>(x, wq_bf, bqkv, qkbuf, vTbuf, xbf, use_xbf);
  k_attn<<<dim3(256), dim3(512), 0, stream>>>(qkbuf, vTbuf, temp, aT);
  k_proj<<<dim3(768), dim3(256), 0, stream>>>(wp_bf, aT, bproj, xbf, x, out, use_xbf);
}

// Round 11
// 124.899 us; speedup vs baseline: 1.0998x; 1.0998x over previous
//
#include <hip/hip_runtime.h>
#include <hip/hip_bf16.h>
#include <stdint.h>

#define BATCH  32
#define CDIM   384
#define NTOK   1024
#define NHEADS 8
#define DH     48

using f32x4  = __attribute__((ext_vector_type(4))) float;
using bf16x8 = __attribute__((ext_vector_type(8))) short;
using u16x4  = __attribute__((ext_vector_type(4))) uint16_t;
using u16x8  = __attribute__((ext_vector_type(8))) uint16_t;

__device__ __forceinline__ uint16_t f2bf(float f) {
  __hip_bfloat16 h = __float2bfloat16(f);   // RNE; compiler packs pairs
  return *reinterpret_cast<uint16_t*>(&h);
}
__device__ __forceinline__ float bf2f(uint16_t u) {
  return __uint_as_float(((uint32_t)u) << 16);
}

#define GLL16(gsrc, ldst)                                                    \
  __builtin_amdgcn_global_load_lds(                                          \
      (const __attribute__((address_space(1))) void*)(gsrc),                 \
      (__attribute__((address_space(3))) void*)(ldst), 16, 0, 0)

// ---- kernel 0: x (B,C,N) f32 -> xT (B,N,C) bf16  [+ xbf (B,C,N) bf16]
//      + folded weight conversion (blockIdx.y == 6 slice) ----
__global__ __launch_bounds__(256) void k_transpose_x(const float* __restrict__ x,
                                                     uint16_t* __restrict__ xT,
                                                     uint16_t* __restrict__ xbf,
                                                     int use_xbf,
                                                     const float* __restrict__ wqkv,
                                                     const float* __restrict__ wproj,
                                                     uint16_t* __restrict__ wq,
                                                     uint16_t* __restrict__ wp) {
  int tid = threadIdx.x;
  if (blockIdx.y == 6) {              // weight-conversion slice (512 blocks)
    int id = blockIdx.x + 16 * blockIdx.z;
    int n1 = 3 * CDIM * CDIM, n2 = CDIM * CDIM;
    for (int i = id * 256 + tid; i < n1 + n2; i += 512 * 256) {
      if (i < n1) wq[i] = f2bf(wqkv[i]);
      else        wp[i - n1] = f2bf(wproj[i - n1]);
    }
    return;
  }
  __shared__ float t[64][65];
  int n0 = blockIdx.x * 64;
  int c0 = blockIdx.y * 64;
  int b  = blockIdx.z;
  const float* xb = x + (size_t)b * CDIM * NTOK;
  uint16_t* xbb = xbf + (size_t)b * CDIM * NTOK;
#pragma unroll
  for (int p = 0; p < 4; ++p) {
    int r  = (tid >> 4) + p * 16;       // channel row
    int cc = (tid & 15) * 4;            // token col chunk
    float4 v = *(const float4*)(xb + (size_t)(c0 + r) * NTOK + n0 + cc);
    t[r][cc + 0] = v.x; t[r][cc + 1] = v.y; t[r][cc + 2] = v.z; t[r][cc + 3] = v.w;
    if (use_xbf) {
      u16x4 o; o[0] = f2bf(v.x); o[1] = f2bf(v.y); o[2] = f2bf(v.z); o[3] = f2bf(v.w);
      *(u16x4*)(xbb + (size_t)(c0 + r) * NTOK + n0 + cc) = o;
    }
  }
  __syncthreads();
  uint16_t* xTb = xT + (size_t)b * NTOK * CDIM;
#pragma unroll
  for (int p = 0; p < 2; ++p) {
    int n  = (tid >> 3) + p * 32;       // token row
    int cb = (tid & 7) * 8;             // channel chunk
    u16x8 o;
#pragma unroll
    for (int j = 0; j < 8; ++j) o[j] = f2bf(t[cb + j][n]);
    *(u16x8*)(xTb + (size_t)(n0 + n) * CDIM + c0 + cb) = o;
  }
}

// ---------------- shared 128x128 GEMM mainloop (K=384, BK=64) ----------------
// Best-measured structure (single 32KB buffer, 2 barriers/K-step, 0 conflicts).
// T2 both-sides swizzle: LDS dest linear (GLL16 requirement), global SOURCE
// chunk pre-permuted by cs = c ^ (row&7); ds_read applies the same involution.
__device__ __forceinline__ void gemm_tile_128(const uint16_t* __restrict__ A,
                                              const uint16_t* __restrict__ B,
                                              uint16_t* ldsA, uint16_t* ldsB,
                                              f32x4 acc[4][4], int tid) {
  const int K = 384;
  int w = tid >> 6, lane = tid & 63;
  int wr = w >> 1, wc = w & 1;
  int lr = lane & 15, g = lane >> 4;
  for (int kt = 0; kt < K; kt += 64) {
    __syncthreads();
#pragma unroll
    for (int iss = 0; iss < 4; ++iss) {
      int ch = tid + 256 * iss;               // 16B chunk index; LDS dest linear
      int r  = ch >> 3;                       // tile row
      int cs = (((ch & 7) ^ (r & 7)) << 3);   // swizzled source elem offset
      GLL16(A + (size_t)r * K + kt + cs, ldsA + (size_t)ch * 8);
      GLL16(B + (size_t)r * K + kt + cs, ldsB + (size_t)ch * 8);
    }
    __syncthreads();
#pragma unroll
    for (int ks = 0; ks < 2; ++ks) {
      bf16x8 af[4], bfr[4];
#pragma unroll
      for (int mt = 0; mt < 4; ++mt) {
        int row = wr * 64 + mt * 16 + lr;
        int sl  = (((ks * 4 + g) ^ (row & 7)) << 3);
        af[mt] = *(const bf16x8*)(ldsA + (size_t)row * 64 + sl);
      }
#pragma unroll
      for (int nt = 0; nt < 4; ++nt) {
        int row = wc * 64 + nt * 16 + lr;
        int sl  = (((ks * 4 + g) ^ (row & 7)) << 3);
        bfr[nt] = *(const bf16x8*)(ldsB + (size_t)row * 64 + sl);
      }
#pragma unroll
      for (int mt = 0; mt < 4; ++mt)
#pragma unroll
        for (int nt = 0; nt < 4; ++nt)
          acc[mt][nt] = __builtin_amdgcn_mfma_f32_16x16x32_bf16(af[mt], bfr[nt], acc[mt][nt], 0, 0, 0);
    }
  }
}

// ---------------- kernel 1: QKV GEMM ----------------
// q,k -> qkbuf (B,768,N) channel-major bf16 ; v -> vT (B,H,N,DH) bf16
// T1 XCD swizzle: 1-D grid 2304 = 8 XCDs x (32 jt x 9 bm).
__global__ __launch_bounds__(256) void k_qkv(const uint16_t* __restrict__ Wq,
                                             const uint16_t* __restrict__ xT,
                                             const float* __restrict__ bqkv,
                                             uint16_t* __restrict__ qk,
                                             uint16_t* __restrict__ vT) {
  __shared__ uint16_t ldsA[128 * 64];
  __shared__ uint16_t ldsB[128 * 64];
  int tid = threadIdx.x;
  int id  = blockIdx.x;
  int xcd = id & 7, idx = id >> 3;          // idx in [0,288)
  int jt  = xcd * 32 + (idx & 31);          // [0,256)
  int bm  = idx >> 5;                       // [0,9)
  int o0 = bm * 128, j0 = jt * 128;
  f32x4 acc[4][4];
#pragma unroll
  for (int i = 0; i < 4; ++i)
#pragma unroll
    for (int j = 0; j < 4; ++j) acc[i][j] = (f32x4){0.f, 0.f, 0.f, 0.f};

  gemm_tile_128(Wq + (size_t)o0 * 384, xT + (size_t)j0 * 384, ldsA, ldsB, acc, tid);

  int w = tid >> 6, lane = tid & 63;
  int wr = w >> 1, wc = w & 1, lr = lane & 15, g = lane >> 4;
#pragma unroll
  for (int mt = 0; mt < 4; ++mt) {
    int ob = o0 + wr * 64 + mt * 16 + g * 4;   // 4 consecutive output rows
    float b0 = bqkv[ob + 0], b1 = bqkv[ob + 1], b2 = bqkv[ob + 2], b3 = bqkv[ob + 3];
#pragma unroll
    for (int nt = 0; nt < 4; ++nt) {
      int j = j0 + wc * 64 + nt * 16 + lr;
      int b = j >> 10, n = j & 1023;
      f32x4 v = acc[mt][nt];
      float v0 = v[0] + b0, v1 = v[1] + b1, v2 = v[2] + b2, v3 = v[3] + b3;
      if (ob < 768) {
        uint16_t* dst = qk + ((size_t)(b * 768 + ob) * 1024 + n);
        dst[0] = f2bf(v0); dst[1024] = f2bf(v1); dst[2048] = f2bf(v2); dst[3072] = f2bf(v3);
      } else {
        int oc = ob - 768;
        int h = oc / 48, d = oc % 48;          // 4-pack never crosses a head (48%4==0)
        u16x4 p;
        p[0] = f2bf(v0); p[1] = f2bf(v1); p[2] = f2bf(v2); p[3] = f2bf(v3);
        *(u16x4*)(vT + ((size_t)((b * 8 + h) * 1024 + n) * 48 + d)) = p;
      }
    }
  }
}

// ---------------- kernel 2: per-(b,h) channel attention (8 waves) ------------
__global__ __launch_bounds__(512) void k_attn(const uint16_t* __restrict__ qk,
                                              const uint16_t* __restrict__ vT,
                                              const float* __restrict__ temperature,
                                              uint16_t* __restrict__ aT) {
  __shared__ float Sp[8][48][49];
  __shared__ float Sf[48][49];
  __shared__ uint16_t P[48][72];   // cols 48..63 zero (K pad), 64..71 unused pad
  __shared__ float nrm[96];
  int tid = threadIdx.x, w = tid >> 6, lane = tid & 63;
  int bh = blockIdx.x, b = bh >> 3, h = bh & 7;
  const uint16_t* qbase = qk + (size_t)(b * 768 + h * 48) * 1024;
  const uint16_t* kbase = qbase + (size_t)384 * 1024;

  // --- L2 norms over N (96 rows, 8 waves x 12 rows) ---
  for (int r = w; r < 96; r += 8) {
    const uint16_t* row = (r < 48) ? (qbase + (size_t)r * 1024)
                                   : (kbase + (size_t)(r - 48) * 1024);
    float s = 0.f;
#pragma unroll
    for (int jj = 0; jj < 4; ++jj) {
      u16x4 u = *(const u16x4*)(row + (size_t)(jj * 64 + lane) * 4);
#pragma unroll
      for (int e = 0; e < 4; ++e) { float f = bf2f(u[e]); s += f * f; }
    }
#pragma unroll
    for (int off = 32; off > 0; off >>= 1) s += __shfl_down(s, off);
    if (lane == 0) nrm[r] = fmaxf(sqrtf(s), 1e-12f);
  }

  // --- S = q . k^T, per-wave K-split (wave w: n in [128w,128w+128)) ---
  int lr = lane & 15, g = lane >> 4;
  int nbase = w * 128;
  f32x4 sacc[3][3];
#pragma unroll
  for (int i = 0; i < 3; ++i)
#pragma unroll
    for (int j = 0; j < 3; ++j) sacc[i][j] = (f32x4){0.f, 0.f, 0.f, 0.f};
#pragma unroll
  for (int ks = 0; ks < 4; ++ks) {
    bf16x8 aq[3], bk[3];
#pragma unroll
    for (int mt = 0; mt < 3; ++mt)
      aq[mt] = *(const bf16x8*)(qbase + (size_t)(mt * 16 + lr) * 1024 + nbase + ks * 32 + g * 8);
#pragma unroll
    for (int et = 0; et < 3; ++et)
      bk[et] = *(const bf16x8*)(kbase + (size_t)(et * 16 + lr) * 1024 + nbase + ks * 32 + g * 8);
#pragma unroll
    for (int mt = 0; mt < 3; ++mt)
#pragma unroll
      for (int et = 0; et < 3; ++et)
        sacc[mt][et] = __builtin_amdgcn_mfma_f32_16x16x32_bf16(aq[mt], bk[et], sacc[mt][et], 0, 0, 0);
  }
#pragma unroll
  for (int mt = 0; mt < 3; ++mt)
#pragma unroll
    for (int et = 0; et < 3; ++et)
#pragma unroll
      for (int r = 0; r < 4; ++r)
        Sp[w][mt * 16 + g * 4 + r][et * 16 + lr] = sacc[mt][et][r];
  __syncthreads();

  // --- reduce partials + scale ---
  float temp = temperature[h];
  for (int idx = tid; idx < 48 * 48; idx += 512) {
    int d = idx / 48, e = idx - d * 48;
    float s = 0.f;
#pragma unroll
    for (int ww = 0; ww < 8; ++ww) s += Sp[ww][d][e];
    Sf[d][e] = s * temp / (nrm[d] * nrm[48 + e]);
  }
  __syncthreads();

  // --- softmax per row -> P (bf16, K-padded with zeros) ---
  if (tid < 48) {
    int d = tid;
    float m = -1e30f;
    for (int e = 0; e < 48; ++e) m = fmaxf(m, Sf[d][e]);
    float sum = 0.f;
    for (int e = 0; e < 48; ++e) { float v = __expf(Sf[d][e] - m); sum += v; Sf[d][e] = v; }
    float inv = 1.f / sum;
    for (int e = 0; e < 48; ++e) P[d][e] = f2bf(Sf[d][e] * inv);
    for (int e = 48; e < 64; ++e) P[d][e] = 0;
  }
  __syncthreads();

  // --- PV: out[d][n] = sum_e P[d][e] v[e][n], v from vT (token-major) ---
  bf16x8 af[3][2];
#pragma unroll
  for (int mt = 0; mt < 3; ++mt)
#pragma unroll
    for (int ks = 0; ks < 2; ++ks)
      af[mt][ks] = *(const bf16x8*)(&P[mt * 16 + lr][ks * 32 + g * 8]);
  const uint16_t* vb = vT + (size_t)(b * 8 + h) * 1024 * 48;
  bf16x8 zf;
#pragma unroll
  for (int i = 0; i < 8; ++i) zf[i] = 0;
#pragma unroll
  for (int nt = 0; nt < 8; ++nt) {
    int n = w * 128 + nt * 16 + lr;
    bf16x8 bv[2];
    bv[0] = *(const bf16x8*)(vb + (size_t)n * 48 + g * 8);
    int eb1 = 32 + g * 8;
    bv[1] = (eb1 < 48) ? *(const bf16x8*)(vb + (size_t)n * 48 + eb1) : zf;
    f32x4 o[3];
#pragma unroll
    for (int mt = 0; mt < 3; ++mt) o[mt] = (f32x4){0.f, 0.f, 0.f, 0.f};
#pragma unroll
    for (int ks = 0; ks < 2; ++ks)
#pragma unroll
      for (int mt = 0; mt < 3; ++mt)
        o[mt] = __builtin_amdgcn_mfma_f32_16x16x32_bf16(af[mt][ks], bv[ks], o[mt], 0, 0, 0);
#pragma unroll
    for (int mt = 0; mt < 3; ++mt) {
      int c = h * 48 + mt * 16 + g * 4;
      u16x4 p;
#pragma unroll
      for (int r = 0; r < 4; ++r) p[r] = f2bf(o[mt][r]);
      *(u16x4*)(aT + ((size_t)(b * 1024 + n) * 384 + c)) = p;
    }
  }
}

// ---------------- kernel 3: proj GEMM + bias + residual ----------------
// T1 XCD swizzle: grid 768 = 8 XCDs x (32 jt x 3 bm).
// Residual from xbf (B,C,N) bf16 when use_xbf; nontemporal out stores
// (128 MB never re-read -> keep aT/xbf/W resident in L2/L3).
__global__ __launch_bounds__(256) void k_proj(const uint16_t* __restrict__ Wp,
                                              const uint16_t* __restrict__ aT,
                                              const float* __restrict__ bproj,
                                              const uint16_t* __restrict__ xbf,
                                              const float* __restrict__ x,
                                              float* __restrict__ out,
                                              int use_xbf) {
  __shared__ uint16_t ldsA[128 * 64];
  __shared__ uint16_t ldsB[128 * 64];
  int tid = threadIdx.x;
  int id  = blockIdx.x;
  int xcd = id & 7, idx = id >> 3;          // idx in [0,96)
  int jt  = xcd * 32 + (idx & 31);          // [0,256)
  int bm  = idx >> 5;                       // [0,3)
  int o0 = bm * 128, j0 = jt * 128;
  f32x4 acc[4][4];
#pragma unroll
  for (int i = 0; i < 4; ++i)
#pragma unroll
    for (int j = 0; j < 4; ++j) acc[i][j] = (f32x4){0.f, 0.f, 0.f, 0.f};

  gemm_tile_128(Wp + (size_t)o0 * 384, aT + (size_t)j0 * 384, ldsA, ldsB, acc, tid);

  int w = tid >> 6, lane = tid & 63;
  int wr = w >> 1, wc = w & 1, lr = lane & 15, g = lane >> 4;
#pragma unroll
  for (int mt = 0; mt < 4; ++mt) {
    int ob = o0 + wr * 64 + mt * 16 + g * 4;
    float b0 = bproj[ob + 0], b1 = bproj[ob + 1], b2 = bproj[ob + 2], b3 = bproj[ob + 3];
#pragma unroll
    for (int nt = 0; nt < 4; ++nt) {
      int j = j0 + wc * 64 + nt * 16 + lr;
      int b = j >> 10, n = j & 1023;
      f32x4 v = acc[mt][nt];
      size_t i0 = (size_t)(b * 384 + ob) * 1024 + n;
      float r0, r1, r2, r3;
      if (use_xbf) {
        r0 = bf2f(xbf[i0]); r1 = bf2f(xbf[i0 + 1024]);
        r2 = bf2f(xbf[i0 + 2048]); r3 = bf2f(xbf[i0 + 3072]);
      } else {
        r0 = x[i0]; r1 = x[i0 + 1024]; r2 = x[i0 + 2048]; r3 = x[i0 + 3072];
      }
      __builtin_nontemporal_store(v[0] + b0 + r0, &out[i0]);
      __builtin_nontemporal_store(v[1] + b1 + r1, &out[i0 + 1024]);
      __builtin_nontemporal_store(v[2] + b2 + r2, &out[i0 + 2048]);
      __builtin_nontemporal_store(v[3] + b3 + r3, &out[i0 + 3072]);
    }
  }
}

extern "C" void kernel_launch(void* const* d_in, const int* in_sizes, int n_in,
                              void* d_out, int out_size, void* d_ws, size_t ws_size,
                              hipStream_t stream) {
  const float* x     = (const float*)d_in[0];
  const float* wqkv  = (const float*)d_in[1];
  const float* bqkv  = (const float*)d_in[2];
  const float* temp  = (const float*)d_in[3];
  const float* wproj = (const float*)d_in[4];
  const float* bproj = (const float*)d_in[5];
  float* out = (float*)d_out;

  char* ws = (char*)d_ws;
  size_t off = 0;
  auto alloc = [&](size_t bytes) -> char* {
    char* p = ws + off;
    off += (bytes + 255) & ~(size_t)255;
    return p;
  };
  uint16_t* xT    = (uint16_t*)alloc((size_t)BATCH * NTOK * CDIM * 2);        // 24 MB
  uint16_t* wq_bf = (uint16_t*)alloc((size_t)3 * CDIM * CDIM * 2);
  uint16_t* wp_bf = (uint16_t*)alloc((size_t)CDIM * CDIM * 2);
  uint16_t* qkbuf = (uint16_t*)alloc((size_t)BATCH * 768 * NTOK * 2);         // 48 MB
  uint16_t* vTbuf = (uint16_t*)alloc((size_t)BATCH * NHEADS * NTOK * DH * 2); // 24 MB
  size_t xbf_bytes = (size_t)BATCH * CDIM * NTOK * 2;                         // 24 MB
  int use_xbf = (off + xbf_bytes <= ws_size) ? 1 : 0;
  uint16_t* xbf = use_xbf ? (uint16_t*)alloc(xbf_bytes) : (uint16_t*)xT; // dummy ptr if unused
  uint16_t* aT  = xT;  // safe alias: xT's last reader (k_qkv) precedes k_attn on the stream

  k_transpose_x<<<dim3(NTOK / 64, 7, BATCH), dim3(256), 0, stream>>>(
      x, xT, xbf, use_xbf, wqkv, wproj, wq_bf, wp_bf);
  k_qkv<<<dim3(2304), dim3(256), 0, stream>>>(wq_bf, xT, bqkv, qkbuf, vTbuf);
  k_attn<<<dim3(256), dim3(512), 0, stream>>>(qkbuf, vTbuf, temp, aT);
  k_proj<<<dim3(768), dim3(256), 0, stream>>>(wp_bf, aT, bproj, xbf, x, out, use_xbf);
}